// Round 11
// baseline (250.348 us; speedup 1.0000x reference)
//
#include <hip/hip_runtime.h>

#define NNODES 50000
#define MPAD   50048    // padded to multiple of 64 for MFMA tiles; rows 50000.. are zero pads
#define NEDGES 800000
#define KDIM   256      // in/hidden feature dim (GEMM K)
#define FH     256      // hidden feats
#define FOUT   128      // out feats
#define FCH    32       // feature chunk (bf16): 64B contiguous per node in blocked layout

// ---- counting-sort geometry ----
#define SHIFT  8
#define NBUCK  196              // ceil(50000/256); max dst>>8 = 195
#define NB1    200              // level-1 blocks
#define EPB    4000             // edges per level-1 block (NB1*EPB == NEDGES)

typedef __bf16 bf16x8 __attribute__((ext_vector_type(8)));
typedef float floatx4 __attribute__((ext_vector_type(4)));
typedef float floatx2 __attribute__((ext_vector_type(2)));

// 16B of indices at 4B alignment (csr segments are not 16B aligned)
struct int4u { int x, y, z, w; };

// ---------------- bf16 helpers (RNE) ----------------
__device__ __forceinline__ float bf2f(unsigned short u) {
    union { unsigned int i; float f; } v;
    v.i = ((unsigned int)u) << 16;
    return v.f;
}
__device__ __forceinline__ unsigned short f2bf(float f) {
    union { float f; unsigned int i; } v;
    v.f = f;
    unsigned int r = v.i + 0x7FFFu + ((v.i >> 16) & 1u);
    return (unsigned short)(r >> 16);
}

// packed bf16-pair accumulate: acc[k] += {lo(d), hi(d)} via v_pk_add_f32
__device__ __forceinline__ void acc_pairs(floatx2* acc, uint4 v) {
    unsigned int d[4] = {v.x, v.y, v.z, v.w};
#pragma unroll
    for (int k = 0; k < 4; ++k) {
        union { unsigned int u; float f; } lo, hi;
        lo.u = d[k] << 16;
        hi.u = d[k] & 0xFFFF0000u;
        floatx2 p = {lo.f, hi.f};
        acc[k] += p;
    }
}

// ============ P1: per-block counting sort, block-major output (no global scan needed)
__global__ __launch_bounds__(256) void l1_sort_cast(const int* __restrict__ src,
                                                    const int* __restrict__ dst,
                                                    unsigned int* __restrict__ tmp1,
                                                    unsigned char* __restrict__ tmp2,
                                                    int* __restrict__ exD_arr,
                                                    int* __restrict__ exS_arr,
                                                    const float* __restrict__ W1,
                                                    unsigned short* __restrict__ Wt1,
                                                    const float* __restrict__ W2,
                                                    unsigned short* __restrict__ Wt2) {
    __shared__ int histD[256], histS[256], exD[256], exS[256];
    __shared__ unsigned int bufD[EPB];
    __shared__ unsigned short bufS[EPB];
    __shared__ float tile[32][33];
    const int tid = threadIdx.x;

    if (blockIdx.x >= NB1) {
        int b = blockIdx.x - NB1;
        const float* W; unsigned short* Wt; int N;
        if (b < 64) { W = W1; Wt = Wt1; N = FH; }
        else        { b -= 64; W = W2; Wt = Wt2; N = FOUT; }
        int kt = (b & 7) * 32;
        int nt = (b >> 3) * 32;
        int tx = tid & 31;
        int ty = tid >> 5;
        for (int r = ty; r < 32; r += 8)
            tile[r][tx] = W[(size_t)(kt + r) * N + nt + tx];
        __syncthreads();
        for (int r = ty; r < 32; r += 8)
            Wt[(size_t)(nt + r) * KDIM + kt + tx] = f2bf(tile[tx][r]);
        return;
    }

    const int b = blockIdx.x;
    const int base = b * EPB;
    histD[tid] = 0; histS[tid] = 0;
    __syncthreads();
    for (int g = tid; g < EPB / 4; g += 256) {
        uint4 s4 = *(const uint4*)(src + base + g * 4);
        uint4 d4 = *(const uint4*)(dst + base + g * 4);
        atomicAdd(&histD[d4.x >> SHIFT], 1);
        atomicAdd(&histD[d4.y >> SHIFT], 1);
        atomicAdd(&histD[d4.z >> SHIFT], 1);
        atomicAdd(&histD[d4.w >> SHIFT], 1);
        atomicAdd(&histS[s4.x >> SHIFT], 1);
        atomicAdd(&histS[s4.y >> SHIFT], 1);
        atomicAdd(&histS[s4.z >> SHIFT], 1);
        atomicAdd(&histS[s4.w >> SHIFT], 1);
    }
    __syncthreads();
    int vD = histD[tid], vS = histS[tid];
    exD[tid] = vD; exS[tid] = vS;
    __syncthreads();
    for (int off = 1; off < 256; off <<= 1) {
        int tD = (tid >= off) ? exD[tid - off] : 0;
        int tS = (tid >= off) ? exS[tid - off] : 0;
        __syncthreads();
        exD[tid] += tD; exS[tid] += tS;
        __syncthreads();
    }
    int eD = exD[tid] - vD, eS = exS[tid] - vS;
    exD_arr[tid * NB1 + b] = eD;
    exS_arr[tid * NB1 + b] = eS;
    __syncthreads();
    histD[tid] = eD; histS[tid] = eS;
    __syncthreads();
    for (int g = tid; g < EPB / 4; g += 256) {
        uint4 s4 = *(const uint4*)(src + base + g * 4);
        uint4 d4 = *(const uint4*)(dst + base + g * 4);
        unsigned int ss[4] = {s4.x, s4.y, s4.z, s4.w};
        unsigned int dd[4] = {d4.x, d4.y, d4.z, d4.w};
#pragma unroll
        for (int j = 0; j < 4; ++j) {
            int p = atomicAdd(&histD[dd[j] >> SHIFT], 1);
            bufD[p] = (ss[j] << 16) | dd[j];
            int q = atomicAdd(&histS[ss[j] >> SHIFT], 1);
            bufS[q] = (unsigned short)ss[j];
        }
    }
    __syncthreads();
    for (int e = tid; e < EPB; e += 256) tmp1[base + e] = bufD[e];
    for (int e = tid; e < EPB; e += 256) tmp2[base + e] = (unsigned char)(bufS[e] & 255u);
}

// ============ P2: per-bucket finalize (dst: row_ptr/norm_dst/csr; src: norm_src) ==========
__global__ __launch_bounds__(256) void l2_both(const unsigned int* __restrict__ tmp1,
                                               const unsigned char* __restrict__ tmp2,
                                               const int* __restrict__ exD_arr,
                                               const int* __restrict__ exS_arr,
                                               int* __restrict__ row_ptr,
                                               float* __restrict__ norm_dst,
                                               float* __restrict__ norm_src,
                                               int* __restrict__ csr_src) {
    __shared__ int cnt[256], ofs[256], cur[256], red[256];
    __shared__ int segoff[NB1], seglen[NB1];
    const int tid = threadIdx.x;

    if (blockIdx.x >= NBUCK) {
        const int k = blockIdx.x - NBUCK;
        if (tid < NB1) {
            int e0 = exS_arr[k * NB1 + tid];
            segoff[tid] = tid * EPB + e0;
            seglen[tid] = exS_arr[(k + 1) * NB1 + tid] - e0;
        }
        cnt[tid] = 0;
        __syncthreads();
        if (tid < NB1) {
            int so = segoff[tid], sl = seglen[tid];
            for (int i = 0; i < sl; ++i)
                atomicAdd(&cnt[tmp2[so + i]], 1);
        }
        __syncthreads();
        int node = k * 256 + tid;
        if (node < NNODES) {
            int d = cnt[tid] < 1 ? 1 : cnt[tid];
            norm_src[node] = 1.0f / sqrtf((float)d);
        }
        return;
    }

    const int k = blockIdx.x;
    int e0v = 0;
    if (tid < NB1) {
        e0v = exD_arr[k * NB1 + tid];
        segoff[tid] = tid * EPB + e0v;
        seglen[tid] = exD_arr[(k + 1) * NB1 + tid] - e0v;
    }
    red[tid] = (tid < NB1) ? e0v : 0;
    cnt[tid] = 0;
    __syncthreads();
    for (int off = 128; off > 0; off >>= 1) {
        if (tid < off) red[tid] += red[tid + off];
        __syncthreads();
    }
    const int base = red[0];
    if (tid < NB1) {
        int so = segoff[tid], sl = seglen[tid];
        for (int i = 0; i < sl; ++i)
            atomicAdd(&cnt[tmp1[so + i] & 255u], 1);
    }
    __syncthreads();
    int v = cnt[tid];
    ofs[tid] = v;
    __syncthreads();
    for (int off = 1; off < 256; off <<= 1) {
        int t = (tid >= off) ? ofs[tid - off] : 0;
        __syncthreads();
        ofs[tid] += t;
        __syncthreads();
    }
    int excl = ofs[tid] - v;
    int node = k * 256 + tid;
    if (node < NNODES) {
        row_ptr[node] = base + excl;
        int d = v < 1 ? 1 : v;
        norm_dst[node] = 1.0f / sqrtf((float)d);
    }
    cur[tid] = base + excl;
    if (k == 0 && tid == 0) row_ptr[NNODES] = NEDGES;
    __syncthreads();
    if (tid < NB1) {
        int so = segoff[tid], sl = seglen[tid];
        for (int i = 0; i < sl; ++i) {
            unsigned int p = tmp1[so + i];
            int pos = atomicAdd(&cur[p & 255u], 1);
            csr_src[pos] = (int)(p >> 16);
        }
    }
}

// ================= Barrier-free-A GEMM =================
// B panel (128 cols x 256 k) LDS-resident ONLY (64KB -> 2 blocks/CU, 4 waves/SIMD).
// A fragments load DIRECTLY from global (one 128B line per row per k-step, L1-shared
// across waves). No barriers after the single B-stage sync -> no vmcnt(0) drains.
// B staged with even/odd column interleave so lane's (a00,a01) = adjacent logical cols
// -> packed 4B C stores. C chunk-blocked [(n/32)][MPAD][32].
__device__ __forceinline__ bf16x8 a_frag(const unsigned short* A, int row, int kk, int fe, float) {
    return *(const bf16x8*)(A + ((size_t)kk * MPAD + row) * FCH + fe);
}
__device__ __forceinline__ bf16x8 a_frag(const float* A, int row, int kk, int fe, float sc) {
    const float* p = A + (size_t)row * KDIM + kk * 32 + fe;
    float4 v0 = *(const float4*)p;
    float4 v1 = *(const float4*)(p + 4);
    union { bf16x8 b; unsigned short s[8]; } r;
    r.s[0] = f2bf(v0.x * sc); r.s[1] = f2bf(v0.y * sc);
    r.s[2] = f2bf(v0.z * sc); r.s[3] = f2bf(v0.w * sc);
    r.s[4] = f2bf(v1.x * sc); r.s[5] = f2bf(v1.y * sc);
    r.s[6] = f2bf(v1.z * sc); r.s[7] = f2bf(v1.w * sc);
    return r.b;
}

template <typename TA, bool SCALE, int NPANEL>
__global__ __launch_bounds__(512) void gemm_bres(const TA* __restrict__ A,
                                                 const unsigned short* __restrict__ Bt,
                                                 const float* __restrict__ norm,
                                                 unsigned short* __restrict__ C) {
    constexpr int NTILES = MPAD / 64;
    __shared__ __align__(16) unsigned short Bs[128 * 256];   // 64KB, [slot][k] swizzled
    char* Bsb = (char*)Bs;

    const int tid = threadIdx.x;
    const int lane = tid & 63;
    const int wave = tid >> 6;

    int col0, mt0, mstep;
    if (NPANEL == 2) {
        col0 = ((blockIdx.x >> 3) & 1) * 128;
        mt0 = ((blockIdx.x >> 4) << 3) + (blockIdx.x & 7);
        mstep = gridDim.x >> 1;
    } else {
        col0 = 0;
        mt0 = blockIdx.x;
        mstep = gridDim.x;
    }

    // ---- stage B once: even/odd col interleave within each 32-group + XOR swizzle ----
    {
        int col = tid >> 2;                 // 0..127
        int kq = (tid & 3) * 64;
        const unsigned short* bg = Bt + (size_t)(col0 + col) * KDIM + kq;
        int w = col & 31;
        int slot = (col & ~31) + ((w & 1) << 4) + (w >> 1);
        const int s = (slot & 7) << 4;
        const int sbase = slot * 512;
#pragma unroll
        for (int j = 0; j < 8; ++j) {
            uint4 v = *(const uint4*)(bg + j * 8);
            *(uint4*)(Bsb + sbase + (((kq + j * 8) * 2) ^ s)) = v;
        }
    }
    __syncthreads();

    const int wn = wave & 3, wm = wave >> 2;
    const int ar = lane & 15;
    const int fe = (lane >> 4) << 3;        // element k-offset 0,8,16,24
    const int fkb = fe * 2;                 // byte offset
    const int cB0 = wn * 32 + ar, cB1 = cB0 + 16;
    const int bO0 = cB0 * 512, bS0 = (cB0 & 7) << 4;
    const int bO1 = cB1 * 512, bS1 = (cB1 & 7) << 4;
    const int rb = (lane >> 4) << 2, cc = lane & 15;
    unsigned short* Cb = C + ((size_t)((col0 >> 5) + wn) * MPAD) * FCH;

    for (int mt = mt0; mt < NTILES; mt += mstep) {
        const int r0 = mt * 64 + wm * 32 + ar;
        const int r1 = r0 + 16;
        int ra0 = r0, ra1 = r1;
        float sc0 = 1.f, sc1 = 1.f;
        if (SCALE) {
            ra0 = (r0 < NNODES) ? r0 : 0; sc0 = (r0 < NNODES) ? norm[r0] : 0.f;
            ra1 = (r1 < NNODES) ? r1 : 0; sc1 = (r1 < NNODES) ? norm[r1] : 0.f;
        }

        floatx4 a00 = {}, a01 = {}, a10 = {}, a11 = {};
#pragma unroll
        for (int kk = 0; kk < 8; ++kk) {
            bf16x8 fa0 = a_frag(A, ra0, kk, fe, sc0);
            bf16x8 fa1 = a_frag(A, ra1, kk, fe, sc1);
            bf16x8 fb0 = *(const bf16x8*)(Bsb + bO0 + ((kk * 64 + fkb) ^ bS0));
            bf16x8 fb1 = *(const bf16x8*)(Bsb + bO1 + ((kk * 64 + fkb) ^ bS1));
            a00 = __builtin_amdgcn_mfma_f32_16x16x32_bf16(fa0, fb0, a00, 0, 0, 0);
            a01 = __builtin_amdgcn_mfma_f32_16x16x32_bf16(fa0, fb1, a01, 0, 0, 0);
            a10 = __builtin_amdgcn_mfma_f32_16x16x32_bf16(fa1, fb0, a10, 0, 0, 0);
            a11 = __builtin_amdgcn_mfma_f32_16x16x32_bf16(fa1, fb1, a11, 0, 0, 0);
        }
        // packed 4B stores: lane cc owns logical cols 2cc (a00/a10) and 2cc+1 (a01/a11)
        const int mB = mt * 64 + wm * 32 + rb;
#pragma unroll
        for (int r = 0; r < 4; ++r) {
            unsigned int u0 = (unsigned int)f2bf(a00[r]) | ((unsigned int)f2bf(a01[r]) << 16);
            unsigned int u1 = (unsigned int)f2bf(a10[r]) | ((unsigned int)f2bf(a11[r]) << 16);
            *(unsigned int*)(Cb + (size_t)(mB + r) * FCH + 2 * cc) = u0;
            *(unsigned int*)(Cb + (size_t)(mB + r + 16) * FCH + 2 * cc) = u1;
        }
    }
}

// ============ agg layer 1: XCD-pinned feature chunk (chunk = blockIdx&7), chunk-blocked
// [8][MPAD][32]. 4 lanes/node x 16B gathers; 8-edge software pipeline (index prefetch),
// packed float2 accumulate (v_pk_add_f32). Pad rows write zeros (ns=0).
__global__ __launch_bounds__(256) void agg1_kernel(const unsigned short* __restrict__ H,
                                                   const int* __restrict__ row_ptr,
                                                   const int* __restrict__ csr_src,
                                                   const float* __restrict__ norm_dst,
                                                   const float* __restrict__ norm_src,
                                                   const float* __restrict__ bias,
                                                   unsigned short* __restrict__ out) {
    const int c = blockIdx.x & 7;
    const int nb = blockIdx.x >> 3;
    const int tid = threadIdx.x;
    const int lane = tid & 63;
    const int g = lane >> 2;         // node slot (0..15)
    const int f0 = (lane & 3) * 8;   // 8 bf16 = 16B
    const int node = nb * 64 + (tid >> 6) * 16 + g;   // < MPAD by grid

    const unsigned short* Hc = H + ((size_t)c * MPAD) * FCH + f0;
    floatx2 acc[4] = {};

    int e0 = 0, e1 = 0;
    if (node < NNODES) { e0 = row_ptr[node]; e1 = row_ptr[node + 1]; }

    if (e0 < e1) {
        int4u ia = *(const int4u*)(csr_src + e0);
        int4u ib = *(const int4u*)(csr_src + e0 + 4);
        for (int e = e0; e < e1; e += 8) {
            const int ecnt = e1 - e;
            int idx[8] = {ia.x, ia.y, ia.z, ia.w, ib.x, ib.y, ib.z, ib.w};
#pragma unroll
            for (int j = 1; j < 8; ++j) idx[j] = (j < ecnt) ? idx[j] : NNODES;
            if (e + 8 < e1) {           // prefetch next indices under the gathers
                ia = *(const int4u*)(csr_src + e + 8);
                ib = *(const int4u*)(csr_src + e + 12);
            }
            uint4 w[8];
#pragma unroll
            for (int j = 0; j < 8; ++j)
                w[j] = *(const uint4*)(Hc + (size_t)idx[j] * FCH);
#pragma unroll
            for (int j = 0; j < 8; ++j) acc_pairs(acc, w[j]);
        }
    }

    float nd = 0.f, ns = 0.f;
    if (node < NNODES) { nd = norm_dst[node]; ns = norm_src[node]; }
    const int fg = c * FCH + f0;
    float4 b0 = *(const float4*)(bias + fg);
    float4 b1v = *(const float4*)(bias + fg + 4);
    float bb[8] = {b0.x, b0.y, b0.z, b0.w, b1v.x, b1v.y, b1v.z, b1v.w};
    union { uint4 u; unsigned short s[8]; } o;
#pragma unroll
    for (int k = 0; k < 4; ++k) {
        o.s[2 * k]     = f2bf(fmaxf(fmaf(acc[k].x, nd, bb[2 * k]), 0.f) * ns);
        o.s[2 * k + 1] = f2bf(fmaxf(fmaf(acc[k].y, nd, bb[2 * k + 1]), 0.f) * ns);
    }
    *(uint4*)(out + ((size_t)c * MPAD + node) * FCH + f0) = o.u;
}

// ============ agg layer 2: 4 chunks, 2 XCDs/chunk. Same 8-edge pipeline + packed acc.
// H chunk-blocked [4][MPAD][32]; out row-major fp32, no relu.
__global__ __launch_bounds__(256) void agg2_kernel(const unsigned short* __restrict__ H,
                                                   const int* __restrict__ row_ptr,
                                                   const int* __restrict__ csr_src,
                                                   const float* __restrict__ norm_dst,
                                                   const float* __restrict__ bias,
                                                   float* __restrict__ out) {
    const int c = (blockIdx.x & 7) >> 1;
    const int nb = (blockIdx.x >> 3) * 2 + (blockIdx.x & 1);
    const int tid = threadIdx.x;
    const int lane = tid & 63;
    const int g = lane >> 2;
    const int f0 = (lane & 3) * 8;
    const int node = nb * 64 + (tid >> 6) * 16 + g;
    if (node >= NNODES) return;

    const unsigned short* Hc = H + ((size_t)c * MPAD) * FCH + f0;
    floatx2 acc[4] = {};

    int e0 = row_ptr[node];
    int e1 = row_ptr[node + 1];

    if (e0 < e1) {
        int4u ia = *(const int4u*)(csr_src + e0);
        int4u ib = *(const int4u*)(csr_src + e0 + 4);
        for (int e = e0; e < e1; e += 8) {
            const int ecnt = e1 - e;
            int idx[8] = {ia.x, ia.y, ia.z, ia.w, ib.x, ib.y, ib.z, ib.w};
#pragma unroll
            for (int j = 1; j < 8; ++j) idx[j] = (j < ecnt) ? idx[j] : NNODES;
            if (e + 8 < e1) {
                ia = *(const int4u*)(csr_src + e + 8);
                ib = *(const int4u*)(csr_src + e + 12);
            }
            uint4 w[8];
#pragma unroll
            for (int j = 0; j < 8; ++j)
                w[j] = *(const uint4*)(Hc + (size_t)idx[j] * FCH);
#pragma unroll
            for (int j = 0; j < 8; ++j) acc_pairs(acc, w[j]);
        }
    }

    float nd = norm_dst[node];
    const int fg = c * FCH + f0;
    float4 b0 = *(const float4*)(bias + fg);
    float4 b1v = *(const float4*)(bias + fg + 4);
    float4 o1, o2;
    o1.x = fmaf(acc[0].x, nd, b0.x);
    o1.y = fmaf(acc[0].y, nd, b0.y);
    o1.z = fmaf(acc[1].x, nd, b0.z);
    o1.w = fmaf(acc[1].y, nd, b0.w);
    o2.x = fmaf(acc[2].x, nd, b1v.x);
    o2.y = fmaf(acc[2].y, nd, b1v.y);
    o2.z = fmaf(acc[3].x, nd, b1v.z);
    o2.w = fmaf(acc[3].y, nd, b1v.w);
    *(float4*)(out + (size_t)node * FOUT + fg) = o1;
    *(float4*)(out + (size_t)node * FOUT + fg + 4) = o2;
}

// ---------------- launch ----------------
extern "C" void kernel_launch(void* const* d_in, const int* in_sizes, int n_in,
                              void* d_out, int out_size, void* d_ws, size_t ws_size,
                              hipStream_t stream) {
    const float* x   = (const float*)d_in[0];
    const int*   src = (const int*)d_in[1];
    const int*   dst = (const int*)d_in[2];
    const float* W1  = (const float*)d_in[3];
    const float* b1  = (const float*)d_in[4];
    const float* W2  = (const float*)d_in[5];
    const float* b2  = (const float*)d_in[6];
    float* out = (float*)d_out;

    char* ws = (char*)d_ws;
    size_t off = 0;
    auto alloc = [&](size_t bytes) {
        char* p = ws + off;
        off += (bytes + 255) & ~(size_t)255;
        return p;
    };
    float* norm_src  = (float*)alloc(NNODES * 4);
    float* norm_dst  = (float*)alloc(NNODES * 4);
    int*   exD_arr   = (int*)alloc((size_t)256 * NB1 * 4);
    int*   exS_arr   = (int*)alloc((size_t)256 * NB1 * 4);
    unsigned int*  tmp1 = (unsigned int*)alloc((size_t)NEDGES * 4);
    unsigned char* tmp2 = (unsigned char*)alloc((size_t)NEDGES);
    int*   row_ptr   = (int*)alloc((NNODES + 16) * 4);
    int*   csr_src   = (int*)alloc((size_t)(NEDGES + 256) * 4);
    unsigned short* h   = (unsigned short*)alloc((size_t)MPAD * FH * 2);
    unsigned short* h1  = (unsigned short*)alloc((size_t)MPAD * FH * 2);
    unsigned short* Wt1 = (unsigned short*)alloc((size_t)FH * KDIM * 2);
    unsigned short* Wt2 = (unsigned short*)alloc((size_t)FOUT * KDIM * 2);
    unsigned short* h2  = h;

    l1_sort_cast<<<NB1 + 96, 256, 0, stream>>>(src, dst, tmp1, tmp2, exD_arr, exS_arr,
                                               W1, Wt1, W2, Wt2);
    l2_both<<<2 * NBUCK, 256, 0, stream>>>(tmp1, tmp2, exD_arr, exS_arr,
                                           row_ptr, norm_dst, norm_src, csr_src);

    // layer 1: h = bf16((x*norm_src) @ W1), chunk-blocked — barrier-free-A, XCD-paired panels
    gemm_bres<float, true, 2><<<512, 512, 0, stream>>>(x, Wt1, norm_src, h);
    agg1_kernel<<<(MPAD / 64) * 8, 256, 0, stream>>>(h, row_ptr, csr_src,
                                                     norm_dst, norm_src, b1, h1);

    // layer 2 — barrier-free-A, single panel, chunk-blocked h1 in / h2 out
    gemm_bres<unsigned short, false, 1><<<512, 512, 0, stream>>>(h1, Wt2, nullptr, h2);
    agg2_kernel<<<((MPAD / 64 + 1) / 2) * 8, 256, 0, stream>>>(h2, row_ptr, csr_src,
                                                               norm_dst, b2, out);
}